// Round 7
// baseline (376.269 us; speedup 1.0000x reference)
//
#include <hip/hip_runtime.h>
#include <math.h>

#define NB 32768
#define NT 48
#define NH 32
#define NOH 16
#define NK 3
#define NS 6
#define NSUB 4

// Force a value to stay live in a VGPR (compiler cannot rematerialize/reload)
#define PIN_V(x) asm volatile("" : "+v"(x))
// Make a wave-uniform float SGPR-resident (legal VGPR->SGPR via readfirstlane)
__device__ __forceinline__ float uni(float x) {
    return __int_as_float(__builtin_amdgcn_readfirstlane(__float_as_int(x)));
}

// partner-lane value via DPP quad_perm [1,0,3,2] (xor lane^1) — VALU pipe, no LDS
__device__ __forceinline__ float dpp_xor1(float v) {
    int x = __builtin_amdgcn_update_dpp(0, __float_as_int(v), 0xB1, 0xF, 0xF, false);
    return __int_as_float(x);
}
__device__ __forceinline__ float qsum2(float v) { return v + dpp_xor1(v); }

// tanh via exact Pade[7/6] from the continued fraction:
// tanh(x) = x*(10395 + 1260u + 21u^2) / (10395 + 4725u + 210u^2 + u^3), u=x^2
// |err| <= 2.2e-5 for |x|<=3, 7.8e-5 at 3.5; clamped beyond (tail err <= 1.9e-3).
// 1 trans (v_rcp, ~1ulp) instead of exp+rcp.
__device__ __forceinline__ float pade_tanh(float x) {
    float xc = fminf(fmaxf(x, -3.5f), 3.5f);
    float u  = xc * xc;
    float N  = fmaf(fmaf(21.0f, u, 1260.0f), u, 10395.0f);
    float D  = fmaf(fmaf(u + 210.0f, u, 4725.0f), u, 10395.0f);
    return xc * N * __builtin_amdgcn_rcpf(D);
}

__device__ __forceinline__ float gelu_exact(float x) {
    return 0.5f * x * (1.0f + erff(x * 0.70710678118654752440f));
}

__global__ void __launch_bounds__(256, 1) pinod_kernel(
    const float* __restrict__ expr,
    const float* __restrict__ t_eval,
    const float* __restrict__ enc_w1,
    const float* __restrict__ enc_b1,
    const float* __restrict__ ln_g,
    const float* __restrict__ ln_b,
    const float* __restrict__ enc_w2,
    const float* __restrict__ enc_b2,
    const float* __restrict__ enc_w3,
    const float* __restrict__ enc_b3,
    const float* __restrict__ periods,
    const float* __restrict__ gammav,
    const float* __restrict__ ode_w1,
    const float* __restrict__ ode_b1,
    const float* __restrict__ ode_w2,
    const float* __restrict__ ode_b2,
    const float* __restrict__ dec_w,
    const float* __restrict__ dec_b,
    const float* __restrict__ baseline,
    float* __restrict__ out)
{
    const int tid    = blockIdx.x * 256 + threadIdx.x;
    const int sub    = tid & 1;          // which half of the hidden units
    const int b      = tid >> 1;         // element id (lane pair {2i,2i+1})
    const int base16 = sub * 16;         // encoder h-unit slice
    const int obase  = sub * 8;          // ODE hidden-unit slice

    float* out_eh  = out;                                          // [NB][NT]
    float* out_tr  = out + (size_t)NB * NT;                        // [NT][NB][NS]
    float* out_amp = out + (size_t)NB * NT + (size_t)NT * NB * NS; // [NB][NK]

    // ======== ODE weights: lane owns 8 hidden units — loaded FIRST and ======
    // ======== pinned into VGPRs so the hot loop never touches memory   ======
    float w1r[NS][8];                  // w1r[i][j] = ode_w1[i][obase+j]
    #pragma unroll
    for (int i = 0; i < NS; ++i) {
        float4 wA = *(const float4*)(ode_w1 + i * NOH + obase);
        float4 wB = *(const float4*)(ode_w1 + i * NOH + obase + 4);
        w1r[i][0] = wA.x; w1r[i][1] = wA.y; w1r[i][2] = wA.z; w1r[i][3] = wA.w;
        w1r[i][4] = wB.x; w1r[i][5] = wB.y; w1r[i][6] = wB.z; w1r[i][7] = wB.w;
    }
    float b1r[8];
    {
        float4 wA = *(const float4*)(ode_b1 + obase);
        float4 wB = *(const float4*)(ode_b1 + obase + 4);
        b1r[0] = wA.x; b1r[1] = wA.y; b1r[2] = wA.z; b1r[3] = wA.w;
        b1r[4] = wB.x; b1r[5] = wB.y; b1r[6] = wB.z; b1r[7] = wB.w;
    }
    float w2r[8][NS];
    #pragma unroll
    for (int j = 0; j < 8; ++j) {
        const float2* wp = (const float2*)(ode_w2 + (obase + j) * NS);
        float2 w0 = wp[0], w1 = wp[1], w2 = wp[2];
        w2r[j][0] = w0.x; w2r[j][1] = w0.y; w2r[j][2] = w1.x;
        w2r[j][3] = w1.y; w2r[j][4] = w2.x; w2r[j][5] = w2.y;
    }
    // half of ode_b2 folded into each lane's pd-accumulator init
    float hb2[NS];
    #pragma unroll
    for (int i = 0; i < NS; ++i) hb2[i] = 0.5f * ode_b2[i];

    #pragma unroll
    for (int i = 0; i < NS; ++i)
        #pragma unroll
        for (int j = 0; j < 8; ++j) PIN_V(w1r[i][j]);
    #pragma unroll
    for (int j = 0; j < 8; ++j) PIN_V(b1r[j]);
    #pragma unroll
    for (int j = 0; j < 8; ++j)
        #pragma unroll
        for (int i = 0; i < NS; ++i) PIN_V(w2r[j][i]);
    #pragma unroll
    for (int i = 0; i < NS; ++i) PIN_V(hb2[i]);

    // uniform scalars -> SGPR-resident via readfirstlane
    float nom2[NK], ntg[NK], dw[NK];
    #pragma unroll
    for (int k = 0; k < NK; ++k) {
        float w = 6.28318530717958647693f / uni(periods[k]);
        nom2[k] = uni(-(w * w));
        ntg[k]  = uni(-2.0f * gammav[k]);
        dw[k]   = uni(dec_w[k]);
    }
    const float addc = uni(dec_b[0] + baseline[0]);

    // ================= encoder (2-way split: 16 h-units per lane) ============
    float h1r[16];
    #pragma unroll
    for (int q = 0; q < 4; ++q) {
        float4 bv = *(const float4*)(enc_b1 + base16 + 4 * q);
        h1r[4 * q] = bv.x; h1r[4 * q + 1] = bv.y; h1r[4 * q + 2] = bv.z; h1r[4 * q + 3] = bv.w;
    }
    const float4* xp = (const float4*)(expr + (size_t)b * NT);
    #pragma unroll 1
    for (int t4 = 0; t4 < NT / 4; ++t4) {
        float4 xq = xp[t4];
        float xs[4] = {xq.x, xq.y, xq.z, xq.w};
        #pragma unroll
        for (int u4 = 0; u4 < 4; ++u4) {
            const float* wr = enc_w1 + (t4 * 4 + u4) * NH + base16;
            float x = xs[u4];
            #pragma unroll
            for (int q = 0; q < 4; ++q) {
                float4 w = *(const float4*)(wr + 4 * q);
                h1r[4 * q]     = fmaf(x, w.x, h1r[4 * q]);
                h1r[4 * q + 1] = fmaf(x, w.y, h1r[4 * q + 1]);
                h1r[4 * q + 2] = fmaf(x, w.z, h1r[4 * q + 2]);
                h1r[4 * q + 3] = fmaf(x, w.w, h1r[4 * q + 3]);
            }
        }
    }
    // layernorm across all 32 (1-stage cross-lane) + gelu
    {
        float s = 0.f;
        #pragma unroll
        for (int u = 0; u < 16; ++u) s += h1r[u];
        float mu = qsum2(s) * (1.0f / NH);
        float v = 0.f;
        #pragma unroll
        for (int u = 0; u < 16; ++u) { float d = h1r[u] - mu; v = fmaf(d, d, v); }
        float var = qsum2(v) * (1.0f / NH);
        float rstd = rsqrtf(var + 1e-5f);
        #pragma unroll
        for (int q = 0; q < 4; ++q) {
            float4 g = *(const float4*)(ln_g + base16 + 4 * q);
            float4 l = *(const float4*)(ln_b + base16 + 4 * q);
            h1r[4 * q]     = gelu_exact((h1r[4 * q]     - mu) * rstd * g.x + l.x);
            h1r[4 * q + 1] = gelu_exact((h1r[4 * q + 1] - mu) * rstd * g.y + l.y);
            h1r[4 * q + 2] = gelu_exact((h1r[4 * q + 2] - mu) * rstd * g.z + l.z);
            h1r[4 * q + 3] = gelu_exact((h1r[4 * q + 3] - mu) * rstd * g.w + l.w);
        }
    }
    // h2 = gelu(h1 @ w2 + b2): lane owns j2 in [base16, base16+16)
    float acc[16];
    #pragma unroll
    for (int q = 0; q < 4; ++q) {
        float4 bv = *(const float4*)(enc_b2 + base16 + 4 * q);
        acc[4 * q] = bv.x; acc[4 * q + 1] = bv.y; acc[4 * q + 2] = bv.z; acc[4 * q + 3] = bv.w;
    }
    #pragma unroll 1
    for (int u = 0; u < 16; ++u) {
        float mine  = h1r[u];                 // value of unit base16+u
        float other = dpp_xor1(mine);         // partner's unit (16-base16)+u
        const float* wa = enc_w2 + (base16 + u) * NH + base16;
        const float* wb = enc_w2 + ((16 - base16) + u) * NH + base16;
        #pragma unroll
        for (int q = 0; q < 4; ++q) {
            float4 w1v = *(const float4*)(wa + 4 * q);
            float4 w2v = *(const float4*)(wb + 4 * q);
            acc[4 * q]     = fmaf(mine, w1v.x, fmaf(other, w2v.x, acc[4 * q]));
            acc[4 * q + 1] = fmaf(mine, w1v.y, fmaf(other, w2v.y, acc[4 * q + 1]));
            acc[4 * q + 2] = fmaf(mine, w1v.z, fmaf(other, w2v.z, acc[4 * q + 2]));
            acc[4 * q + 3] = fmaf(mine, w1v.w, fmaf(other, w2v.w, acc[4 * q + 3]));
        }
    }
    // z0 = gelu(acc) @ w3 + b3, 1-stage reduce -> replicated in both lanes
    float z[NS];
    {
        float zp[NS] = {0.f, 0.f, 0.f, 0.f, 0.f, 0.f};
        #pragma unroll 1
        for (int u = 0; u < 16; ++u) {
            float gm = gelu_exact(acc[u]);
            const float2* wp = (const float2*)(enc_w3 + (base16 + u) * NS);
            float2 w0 = wp[0], w1 = wp[1], w2 = wp[2];
            zp[0] = fmaf(gm, w0.x, zp[0]); zp[1] = fmaf(gm, w0.y, zp[1]);
            zp[2] = fmaf(gm, w1.x, zp[2]); zp[3] = fmaf(gm, w1.y, zp[3]);
            zp[4] = fmaf(gm, w2.x, zp[4]); zp[5] = fmaf(gm, w2.y, zp[5]);
        }
        #pragma unroll
        for (int s = 0; s < NS; ++s) z[s] = qsum2(zp[s]) + enc_b3[s];
    }

    auto deriv = [&](const float (&zz)[NS], float (&d)[NS]) {
        float a[8];
        #pragma unroll
        for (int j = 0; j < 8; ++j) a[j] = b1r[j];
        #pragma unroll
        for (int i = 0; i < NS; ++i) {
            #pragma unroll
            for (int j = 0; j < 8; ++j) a[j] = fmaf(zz[i], w1r[i][j], a[j]);
        }
        float y[8];
        #pragma unroll
        for (int j = 0; j < 8; ++j) y[j] = pade_tanh(a[j]);
        float pd[NS];
        #pragma unroll
        for (int i = 0; i < NS; ++i) pd[i] = hb2[i];   // b2 folded (x2 via reduce)
        #pragma unroll
        for (int j = 0; j < 8; ++j) {
            #pragma unroll
            for (int i = 0; i < NS; ++i) pd[i] = fmaf(y[j], w2r[j][i], pd[i]);
        }
        #pragma unroll
        for (int i = 0; i < NS; ++i) pd[i] = qsum2(pd[i]);
        #pragma unroll
        for (int k = 0; k < NK; ++k) {
            float xx = zz[2 * k], vv = zz[2 * k + 1];
            d[2 * k]     = vv + pd[2 * k];
            d[2 * k + 1] = fmaf(nom2[k], xx, ntg[k] * vv) + pd[2 * k + 1];
        }
    };

    // ================= t = 0 outputs =================
    float amp[NK];
    {
        float eh = addc;
        #pragma unroll
        for (int k = 0; k < NK; ++k) {
            float xx = z[2 * k];
            amp[k] = xx * xx;
            eh = fmaf(xx, dw[k], eh);
        }
        float* tp = out_tr + (size_t)b * NS;
        if (sub == 0) {
            out_eh[(size_t)b * NT] = eh;
            float2 s0 = {z[0], z[1]}, s1 = {z[2], z[3]};
            *(float2*)tp = s0; *(float2*)(tp + 2) = s1;
        } else {
            float2 s2 = {z[4], z[5]};
            *(float2*)(tp + 4) = s2;
        }
    }

    // ================= integrate =================
    float te_prev = t_eval[0];
    #pragma unroll 1
    for (int t = 1; t < NT; ++t) {
        const float te  = t_eval[t];
        const float dt  = te - te_prev;
        te_prev = te;
        const float hh  = dt * (1.0f / NSUB);
        const float hh2 = 0.5f * hh;
        const float hh6 = hh * (1.0f / 6.0f);
        #pragma unroll 1
        for (int ss = 0; ss < NSUB; ++ss) {
            float d[NS], zt[NS], zs[NS];
            deriv(z, d);                                        // k1
            #pragma unroll
            for (int i = 0; i < NS; ++i) { zs[i] = d[i]; zt[i] = fmaf(hh2, d[i], z[i]); }
            deriv(zt, d);                                       // k2
            #pragma unroll
            for (int i = 0; i < NS; ++i) { zs[i] = fmaf(2.f, d[i], zs[i]); zt[i] = fmaf(hh2, d[i], z[i]); }
            deriv(zt, d);                                       // k3
            #pragma unroll
            for (int i = 0; i < NS; ++i) { zs[i] = fmaf(2.f, d[i], zs[i]); zt[i] = fmaf(hh, d[i], z[i]); }
            deriv(zt, d);                                       // k4
            #pragma unroll
            for (int i = 0; i < NS; ++i) z[i] = fmaf(hh6, zs[i] + d[i], z[i]);
        }
        float eh = addc;
        #pragma unroll
        for (int k = 0; k < NK; ++k) {
            float xx = z[2 * k];
            amp[k] = fmaf(xx, xx, amp[k]);
            eh = fmaf(xx, dw[k], eh);
        }
        float* tp = out_tr + ((size_t)t * NB + b) * NS;
        if (sub == 0) {
            out_eh[(size_t)b * NT + t] = eh;
            float2 s0 = {z[0], z[1]}, s1 = {z[2], z[3]};
            *(float2*)tp = s0; *(float2*)(tp + 2) = s1;
        } else {
            float2 s2 = {z[4], z[5]};
            *(float2*)(tp + 4) = s2;
        }
    }

    if (sub == 0) {
        out_amp[(size_t)b * NK]     = sqrtf(amp[0] * (1.0f / NT));
        out_amp[(size_t)b * NK + 1] = sqrtf(amp[1] * (1.0f / NT));
    } else {
        out_amp[(size_t)b * NK + 2] = sqrtf(amp[2] * (1.0f / NT));
    }
}

extern "C" void kernel_launch(void* const* d_in, const int* in_sizes, int n_in,
                              void* d_out, int out_size, void* d_ws, size_t ws_size,
                              hipStream_t stream) {
    pinod_kernel<<<(NB * 2) / 256, 256, 0, stream>>>(
        (const float*)d_in[0],  (const float*)d_in[1],  (const float*)d_in[2],
        (const float*)d_in[3],  (const float*)d_in[4],  (const float*)d_in[5],
        (const float*)d_in[6],  (const float*)d_in[7],  (const float*)d_in[8],
        (const float*)d_in[9],  (const float*)d_in[10], (const float*)d_in[11],
        (const float*)d_in[12], (const float*)d_in[13], (const float*)d_in[14],
        (const float*)d_in[15], (const float*)d_in[16], (const float*)d_in[17],
        (const float*)d_in[18], (float*)d_out);
}

// Round 8
// 300.269 us; speedup vs baseline: 1.2531x; 1.2531x over previous
//
#include <hip/hip_runtime.h>
#include <math.h>

#define NB 32768
#define NT 48
#define NH 32
#define NOH 16
#define NK 3
#define NS 6
#define NSUB 4

typedef float f2 __attribute__((ext_vector_type(2)));

// Force a value/pair to stay live in VGPRs (compiler cannot rematerialize)
#define PIN_V(x) asm volatile("" : "+v"(x))
// Make a wave-uniform float SGPR-resident (legal VGPR->SGPR via readfirstlane)
__device__ __forceinline__ float uni(float x) {
    return __int_as_float(__builtin_amdgcn_readfirstlane(__float_as_int(x)));
}

// packed fma with scalar broadcast via op_sel:
//   LO: acc.{x,y} += zp.x * w.{x,y}      HI: acc.{x,y} += zp.y * w.{x,y}
#define PK_FMA_LO(acc, zp, w) \
    asm("v_pk_fma_f32 %0, %1, %2, %0 op_sel:[0,0,0] op_sel_hi:[0,1,1]" \
        : "+v"(acc) : "v"(zp), "v"(w))
#define PK_FMA_HI(acc, zp, w) \
    asm("v_pk_fma_f32 %0, %1, %2, %0 op_sel:[1,0,0] op_sel_hi:[1,1,1]" \
        : "+v"(acc) : "v"(zp), "v"(w))

__device__ __forceinline__ f2 fma2(f2 a, f2 b, f2 c) {
    return __builtin_elementwise_fma(a, b, c);
}
__device__ __forceinline__ f2 bc2(float x) { f2 r; r.x = x; r.y = x; return r; }

// partner-lane value via DPP quad_perm [1,0,3,2] (xor lane^1) — VALU pipe
__device__ __forceinline__ float dpp_xor1(float v) {
    int x = __builtin_amdgcn_update_dpp(0, __float_as_int(v), 0xB1, 0xF, 0xF, false);
    return __int_as_float(x);
}
__device__ __forceinline__ float qsum2(float v) { return v + dpp_xor1(v); }

__device__ __forceinline__ float gelu_exact(float x) {
    return 0.5f * x * (1.0f + erff(x * 0.70710678118654752440f));
}
__device__ __forceinline__ float fast_tanh(float x) {
    float e = __builtin_amdgcn_exp2f(2.88539008177792681472f * x);
    return 1.0f - 2.0f * __builtin_amdgcn_rcpf(e + 1.0f);
}

__global__ void __launch_bounds__(256, 1) pinod_kernel(
    const float* __restrict__ expr,
    const float* __restrict__ t_eval,
    const float* __restrict__ enc_w1,
    const float* __restrict__ enc_b1,
    const float* __restrict__ ln_g,
    const float* __restrict__ ln_b,
    const float* __restrict__ enc_w2,
    const float* __restrict__ enc_b2,
    const float* __restrict__ enc_w3,
    const float* __restrict__ enc_b3,
    const float* __restrict__ periods,
    const float* __restrict__ gammav,
    const float* __restrict__ ode_w1,
    const float* __restrict__ ode_b1,
    const float* __restrict__ ode_w2,
    const float* __restrict__ ode_b2,
    const float* __restrict__ dec_w,
    const float* __restrict__ dec_b,
    const float* __restrict__ baseline,
    float* __restrict__ out)
{
    const int tid    = blockIdx.x * 256 + threadIdx.x;
    const int sub    = tid & 1;          // which half of the hidden units
    const int b      = tid >> 1;         // element id (lane pair {2i,2i+1})
    const int base16 = sub * 16;         // encoder h-unit slice
    const int obase  = sub * 8;          // ODE hidden-unit slice

    float* out_eh  = out;                                          // [NB][NT]
    float* out_tr  = out + (size_t)NB * NT;                        // [NT][NB][NS]
    float* out_amp = out + (size_t)NB * NT + (size_t)NT * NB * NS; // [NB][NK]

    // ======== ODE weights as f2 pairs, pinned VGPR-resident ========
    // w1p[i][p] = ode_w1[i][obase+2p .. +1]  (i = state, p = unit-pair)
    f2 w1p[NS][4];
    #pragma unroll
    for (int i = 0; i < NS; ++i) {
        float4 wA = *(const float4*)(ode_w1 + i * NOH + obase);
        float4 wB = *(const float4*)(ode_w1 + i * NOH + obase + 4);
        w1p[i][0].x = wA.x; w1p[i][0].y = wA.y;
        w1p[i][1].x = wA.z; w1p[i][1].y = wA.w;
        w1p[i][2].x = wB.x; w1p[i][2].y = wB.y;
        w1p[i][3].x = wB.z; w1p[i][3].y = wB.w;
    }
    f2 b1p[4];
    {
        float4 wA = *(const float4*)(ode_b1 + obase);
        float4 wB = *(const float4*)(ode_b1 + obase + 4);
        b1p[0].x = wA.x; b1p[0].y = wA.y; b1p[1].x = wA.z; b1p[1].y = wA.w;
        b1p[2].x = wB.x; b1p[2].y = wB.y; b1p[3].x = wB.z; b1p[3].y = wB.w;
    }
    // w2p[j][s] = ode_w2[obase+j][2s .. +1]  (j = unit, s = state-pair)
    f2 w2p[8][3];
    #pragma unroll
    for (int j = 0; j < 8; ++j) {
        const float2* wp = (const float2*)(ode_w2 + (obase + j) * NS);
        #pragma unroll
        for (int s = 0; s < 3; ++s) { float2 w = wp[s]; w2p[j][s].x = w.x; w2p[j][s].y = w.y; }
    }
    // half of ode_b2 folded into each lane's pd init (x2 via cross-lane sum)
    f2 hb2p[3];
    #pragma unroll
    for (int s = 0; s < 3; ++s) {
        float2 w = *(const float2*)(ode_b2 + 2 * s);
        hb2p[s].x = 0.5f * w.x; hb2p[s].y = 0.5f * w.y;
    }
    f2 c288p; c288p.x = 2.88539008177792681472f; c288p.y = c288p.x;

    #pragma unroll
    for (int i = 0; i < NS; ++i)
        #pragma unroll
        for (int p = 0; p < 4; ++p) PIN_V(w1p[i][p]);
    #pragma unroll
    for (int p = 0; p < 4; ++p) PIN_V(b1p[p]);
    #pragma unroll
    for (int j = 0; j < 8; ++j)
        #pragma unroll
        for (int s = 0; s < 3; ++s) PIN_V(w2p[j][s]);
    #pragma unroll
    for (int s = 0; s < 3; ++s) PIN_V(hb2p[s]);
    PIN_V(c288p);

    // uniform scalars -> SGPR-resident
    float nom2[NK], ntg[NK], dw[NK];
    #pragma unroll
    for (int k = 0; k < NK; ++k) {
        float w = 6.28318530717958647693f / uni(periods[k]);
        nom2[k] = uni(-(w * w));
        ntg[k]  = uni(-2.0f * gammav[k]);
        dw[k]   = uni(dec_w[k]);
    }
    const float addc = uni(dec_b[0] + baseline[0]);

    // ================= encoder (2-way split: 16 h-units per lane) ============
    float h1r[16];
    #pragma unroll
    for (int q = 0; q < 4; ++q) {
        float4 bv = *(const float4*)(enc_b1 + base16 + 4 * q);
        h1r[4 * q] = bv.x; h1r[4 * q + 1] = bv.y; h1r[4 * q + 2] = bv.z; h1r[4 * q + 3] = bv.w;
    }
    const float4* xp = (const float4*)(expr + (size_t)b * NT);
    #pragma unroll 1
    for (int t4 = 0; t4 < NT / 4; ++t4) {
        float4 xq = xp[t4];
        float xs[4] = {xq.x, xq.y, xq.z, xq.w};
        #pragma unroll
        for (int u4 = 0; u4 < 4; ++u4) {
            const float* wr = enc_w1 + (t4 * 4 + u4) * NH + base16;
            float x = xs[u4];
            #pragma unroll
            for (int q = 0; q < 4; ++q) {
                float4 w = *(const float4*)(wr + 4 * q);
                h1r[4 * q]     = fmaf(x, w.x, h1r[4 * q]);
                h1r[4 * q + 1] = fmaf(x, w.y, h1r[4 * q + 1]);
                h1r[4 * q + 2] = fmaf(x, w.z, h1r[4 * q + 2]);
                h1r[4 * q + 3] = fmaf(x, w.w, h1r[4 * q + 3]);
            }
        }
    }
    // layernorm across all 32 (1-stage cross-lane) + gelu
    {
        float s = 0.f;
        #pragma unroll
        for (int u = 0; u < 16; ++u) s += h1r[u];
        float mu = qsum2(s) * (1.0f / NH);
        float v = 0.f;
        #pragma unroll
        for (int u = 0; u < 16; ++u) { float d = h1r[u] - mu; v = fmaf(d, d, v); }
        float var = qsum2(v) * (1.0f / NH);
        float rstd = rsqrtf(var + 1e-5f);
        #pragma unroll
        for (int q = 0; q < 4; ++q) {
            float4 g = *(const float4*)(ln_g + base16 + 4 * q);
            float4 l = *(const float4*)(ln_b + base16 + 4 * q);
            h1r[4 * q]     = gelu_exact((h1r[4 * q]     - mu) * rstd * g.x + l.x);
            h1r[4 * q + 1] = gelu_exact((h1r[4 * q + 1] - mu) * rstd * g.y + l.y);
            h1r[4 * q + 2] = gelu_exact((h1r[4 * q + 2] - mu) * rstd * g.z + l.z);
            h1r[4 * q + 3] = gelu_exact((h1r[4 * q + 3] - mu) * rstd * g.w + l.w);
        }
    }
    // h2 = gelu(h1 @ w2 + b2): lane owns j2 in [base16, base16+16)
    float acc[16];
    #pragma unroll
    for (int q = 0; q < 4; ++q) {
        float4 bv = *(const float4*)(enc_b2 + base16 + 4 * q);
        acc[4 * q] = bv.x; acc[4 * q + 1] = bv.y; acc[4 * q + 2] = bv.z; acc[4 * q + 3] = bv.w;
    }
    #pragma unroll 1
    for (int u = 0; u < 16; ++u) {
        float mine  = h1r[u];
        float other = dpp_xor1(mine);
        const float* wa = enc_w2 + (base16 + u) * NH + base16;
        const float* wb = enc_w2 + ((16 - base16) + u) * NH + base16;
        #pragma unroll
        for (int q = 0; q < 4; ++q) {
            float4 w1v = *(const float4*)(wa + 4 * q);
            float4 w2v = *(const float4*)(wb + 4 * q);
            acc[4 * q]     = fmaf(mine, w1v.x, fmaf(other, w2v.x, acc[4 * q]));
            acc[4 * q + 1] = fmaf(mine, w1v.y, fmaf(other, w2v.y, acc[4 * q + 1]));
            acc[4 * q + 2] = fmaf(mine, w1v.z, fmaf(other, w2v.z, acc[4 * q + 2]));
            acc[4 * q + 3] = fmaf(mine, w1v.w, fmaf(other, w2v.w, acc[4 * q + 3]));
        }
    }
    // z0 = gelu(acc) @ w3 + b3, 1-stage reduce -> replicated in both lanes
    f2 z[3];
    {
        float zp[NS] = {0.f, 0.f, 0.f, 0.f, 0.f, 0.f};
        #pragma unroll 1
        for (int u = 0; u < 16; ++u) {
            float gm = gelu_exact(acc[u]);
            const float2* wp = (const float2*)(enc_w3 + (base16 + u) * NS);
            float2 w0 = wp[0], w1 = wp[1], w2 = wp[2];
            zp[0] = fmaf(gm, w0.x, zp[0]); zp[1] = fmaf(gm, w0.y, zp[1]);
            zp[2] = fmaf(gm, w1.x, zp[2]); zp[3] = fmaf(gm, w1.y, zp[3]);
            zp[4] = fmaf(gm, w2.x, zp[4]); zp[5] = fmaf(gm, w2.y, zp[5]);
        }
        #pragma unroll
        for (int s = 0; s < 3; ++s) {
            z[s].x = qsum2(zp[2 * s])     + enc_b3[2 * s];
            z[s].y = qsum2(zp[2 * s + 1]) + enc_b3[2 * s + 1];
        }
    }

    auto deriv = [&](const f2 (&zz)[3], f2 (&d)[3]) {
        // a[p] = b1 + sum_i z_i * w1[i][pair p] — packed, op_sel broadcast
        f2 a[4];
        #pragma unroll
        for (int p = 0; p < 4; ++p) a[p] = b1p[p];
        #pragma unroll
        for (int s = 0; s < 3; ++s) {
            #pragma unroll
            for (int p = 0; p < 4; ++p) {
                PK_FMA_LO(a[p], zz[s], w1p[2 * s][p]);
                PK_FMA_HI(a[p], zz[s], w1p[2 * s + 1][p]);
            }
        }
        // tanh on pairs: 1 - 2/(exp2(c*x)+1)
        f2 y[4];
        #pragma unroll
        for (int p = 0; p < 4; ++p) {
            f2 t = a[p] * c288p;
            f2 e; e.x = __builtin_amdgcn_exp2f(t.x); e.y = __builtin_amdgcn_exp2f(t.y);
            f2 r = e + bc2(1.0f);
            f2 rc; rc.x = __builtin_amdgcn_rcpf(r.x); rc.y = __builtin_amdgcn_rcpf(r.y);
            y[p] = fma2(bc2(-2.0f), rc, bc2(1.0f));
        }
        // pd[s] = hb2 + sum_j y_j * w2[j][pair s] — packed, op_sel broadcast
        f2 pd[3];
        #pragma unroll
        for (int s = 0; s < 3; ++s) pd[s] = hb2p[s];
        #pragma unroll
        for (int p = 0; p < 4; ++p) {
            #pragma unroll
            for (int s = 0; s < 3; ++s) {
                PK_FMA_LO(pd[s], y[p], w2p[2 * p][s]);
                PK_FMA_HI(pd[s], y[p], w2p[2 * p + 1][s]);
            }
        }
        // cross-lane reduce + assemble base dynamics
        #pragma unroll
        for (int s = 0; s < 3; ++s) {
            f2 o; o.x = dpp_xor1(pd[s].x); o.y = dpp_xor1(pd[s].y);
            pd[s] += o;
            float xx = zz[s].x, vv = zz[s].y;
            d[s].x = vv + pd[s].x;
            d[s].y = fmaf(nom2[s], xx, ntg[s] * vv) + pd[s].y;
        }
    };

    // ================= t = 0 outputs =================
    float amp[NK];
    {
        float eh = addc;
        #pragma unroll
        for (int k = 0; k < NK; ++k) {
            float xx = z[k].x;
            amp[k] = xx * xx;
            eh = fmaf(xx, dw[k], eh);
        }
        float* tp = out_tr + (size_t)b * NS;
        if (sub == 0) {
            out_eh[(size_t)b * NT] = eh;
            float2 s0 = {z[0].x, z[0].y}, s1 = {z[1].x, z[1].y};
            *(float2*)tp = s0; *(float2*)(tp + 2) = s1;
        } else {
            float2 s2 = {z[2].x, z[2].y};
            *(float2*)(tp + 4) = s2;
        }
    }

    // ================= integrate =================
    float te_prev = t_eval[0];
    #pragma unroll 1
    for (int t = 1; t < NT; ++t) {
        const float te  = t_eval[t];
        const float dt  = te - te_prev;
        te_prev = te;
        const float hh  = dt * (1.0f / NSUB);
        const float hh2 = 0.5f * hh;
        const float hh6 = hh * (1.0f / 6.0f);
        f2 hh2p = bc2(hh2), hhp = bc2(hh), hh6p = bc2(hh6);
        #pragma unroll 1
        for (int ss = 0; ss < NSUB; ++ss) {
            f2 d[3], zt[3], zs[3];
            deriv(z, d);                                        // k1
            #pragma unroll
            for (int s = 0; s < 3; ++s) { zs[s] = d[s]; zt[s] = fma2(hh2p, d[s], z[s]); }
            deriv(zt, d);                                       // k2
            #pragma unroll
            for (int s = 0; s < 3; ++s) { zs[s] = fma2(bc2(2.f), d[s], zs[s]); zt[s] = fma2(hh2p, d[s], z[s]); }
            deriv(zt, d);                                       // k3
            #pragma unroll
            for (int s = 0; s < 3; ++s) { zs[s] = fma2(bc2(2.f), d[s], zs[s]); zt[s] = fma2(hhp, d[s], z[s]); }
            deriv(zt, d);                                       // k4
            #pragma unroll
            for (int s = 0; s < 3; ++s) z[s] = fma2(hh6p, zs[s] + d[s], z[s]);
        }
        float eh = addc;
        #pragma unroll
        for (int k = 0; k < NK; ++k) {
            float xx = z[k].x;
            amp[k] = fmaf(xx, xx, amp[k]);
            eh = fmaf(xx, dw[k], eh);
        }
        float* tp = out_tr + ((size_t)t * NB + b) * NS;
        if (sub == 0) {
            out_eh[(size_t)b * NT + t] = eh;
            float2 s0 = {z[0].x, z[0].y}, s1 = {z[1].x, z[1].y};
            *(float2*)tp = s0; *(float2*)(tp + 2) = s1;
        } else {
            float2 s2 = {z[2].x, z[2].y};
            *(float2*)(tp + 4) = s2;
        }
    }

    if (sub == 0) {
        out_amp[(size_t)b * NK]     = sqrtf(amp[0] * (1.0f / NT));
        out_amp[(size_t)b * NK + 1] = sqrtf(amp[1] * (1.0f / NT));
    } else {
        out_amp[(size_t)b * NK + 2] = sqrtf(amp[2] * (1.0f / NT));
    }
}

extern "C" void kernel_launch(void* const* d_in, const int* in_sizes, int n_in,
                              void* d_out, int out_size, void* d_ws, size_t ws_size,
                              hipStream_t stream) {
    pinod_kernel<<<(NB * 2) / 256, 256, 0, stream>>>(
        (const float*)d_in[0],  (const float*)d_in[1],  (const float*)d_in[2],
        (const float*)d_in[3],  (const float*)d_in[4],  (const float*)d_in[5],
        (const float*)d_in[6],  (const float*)d_in[7],  (const float*)d_in[8],
        (const float*)d_in[9],  (const float*)d_in[10], (const float*)d_in[11],
        (const float*)d_in[12], (const float*)d_in[13], (const float*)d_in[14],
        (const float*)d_in[15], (const float*)d_in[16], (const float*)d_in[17],
        (const float*)d_in[18], (float*)d_out);
}

// Round 9
// 287.051 us; speedup vs baseline: 1.3108x; 1.0461x over previous
//
#include <hip/hip_runtime.h>
#include <math.h>

#define NB 32768
#define NT 48
#define NH 32
#define NOH 16
#define NK 3
#define NS 6
#define NSUB 4

typedef float f2 __attribute__((ext_vector_type(2)));

// Force a value/pair to stay live in VGPRs (compiler cannot rematerialize)
#define PIN_V(x) asm volatile("" : "+v"(x))
// Make a wave-uniform float SGPR-resident (legal VGPR->SGPR via readfirstlane)
__device__ __forceinline__ float uni(float x) {
    return __int_as_float(__builtin_amdgcn_readfirstlane(__float_as_int(x)));
}

// packed fma, src0 scalar-broadcast via op_sel (verified semantics in R7):
//   LO: acc.{x,y} += zp.x * w.{x,y}      HI: acc.{x,y} += zp.y * w.{x,y}
#define PK_FMA_LO(acc, zp, w) \
    asm("v_pk_fma_f32 %0, %1, %2, %0 op_sel:[0,0,0] op_sel_hi:[0,1,1]" \
        : "+v"(acc) : "v"(zp), "v"(w))
#define PK_FMA_HI(acc, zp, w) \
    asm("v_pk_fma_f32 %0, %1, %2, %0 op_sel:[1,0,0] op_sel_hi:[1,1,1]" \
        : "+v"(acc) : "v"(zp), "v"(w))
// init forms: dst = bcast(zp)*w + c   (no accumulator-copy mov)
#define PK_FMA_LO_I(dst, zp, w, c) \
    asm("v_pk_fma_f32 %0, %1, %2, %3 op_sel:[0,0,0] op_sel_hi:[0,1,1]" \
        : "=v"(dst) : "v"(zp), "v"(w), "v"(c))
// swapped src0: lo-result uses zp.hi, hi-result uses zp.lo
#define PK_FMA_SWAP_I(dst, zp, cc, c) \
    asm("v_pk_fma_f32 %0, %1, %2, %3 op_sel:[1,0,0] op_sel_hi:[0,1,1]" \
        : "=v"(dst) : "v"(zp), "v"(cc), "v"(c))

__device__ __forceinline__ f2 fma2(f2 a, f2 b, f2 c) {
    return __builtin_elementwise_fma(a, b, c);
}
__device__ __forceinline__ f2 bc2(float x) { f2 r; r.x = x; r.y = x; return r; }

// partner-lane value via DPP quad_perm [1,0,3,2] (xor lane^1) — VALU pipe
__device__ __forceinline__ float dpp_xor1(float v) {
    int x = __builtin_amdgcn_update_dpp(0, __float_as_int(v), 0xB1, 0xF, 0xF, false);
    return __int_as_float(x);
}
__device__ __forceinline__ float qsum2(float v) { return v + dpp_xor1(v); }

__device__ __forceinline__ float gelu_exact(float x) {
    return 0.5f * x * (1.0f + erff(x * 0.70710678118654752440f));
}

__global__ void __launch_bounds__(256, 1) pinod_kernel(
    const float* __restrict__ expr,
    const float* __restrict__ t_eval,
    const float* __restrict__ enc_w1,
    const float* __restrict__ enc_b1,
    const float* __restrict__ ln_g,
    const float* __restrict__ ln_b,
    const float* __restrict__ enc_w2,
    const float* __restrict__ enc_b2,
    const float* __restrict__ enc_w3,
    const float* __restrict__ enc_b3,
    const float* __restrict__ periods,
    const float* __restrict__ gammav,
    const float* __restrict__ ode_w1,
    const float* __restrict__ ode_b1,
    const float* __restrict__ ode_w2,
    const float* __restrict__ ode_b2,
    const float* __restrict__ dec_w,
    const float* __restrict__ dec_b,
    const float* __restrict__ baseline,
    float* __restrict__ out)
{
    const int tid    = blockIdx.x * 256 + threadIdx.x;
    const int sub    = tid & 1;          // which half of the hidden units
    const int b      = tid >> 1;         // element id (lane pair {2i,2i+1})
    const int base16 = sub * 16;         // encoder h-unit slice
    const int obase  = sub * 8;          // ODE hidden-unit slice

    float* out_eh  = out;                                          // [NB][NT]
    float* out_tr  = out + (size_t)NB * NT;                        // [NT][NB][NS]
    float* out_amp = out + (size_t)NB * NT + (size_t)NT * NB * NS; // [NB][NK]

    const float C = 2.88539008177792681472f;   // 2*log2(e), folded into w1/b1

    // ======== ODE weights as f2 pairs, algebraically folded + pinned ========
    // w1p[i][p] = C * ode_w1[i][obase+2p .. +1]
    f2 w1p[NS][4];
    #pragma unroll
    for (int i = 0; i < NS; ++i) {
        float4 wA = *(const float4*)(ode_w1 + i * NOH + obase);
        float4 wB = *(const float4*)(ode_w1 + i * NOH + obase + 4);
        w1p[i][0].x = C * wA.x; w1p[i][0].y = C * wA.y;
        w1p[i][1].x = C * wA.z; w1p[i][1].y = C * wA.w;
        w1p[i][2].x = C * wB.x; w1p[i][2].y = C * wB.y;
        w1p[i][3].x = C * wB.z; w1p[i][3].y = C * wB.w;
    }
    f2 b1p[4];
    {
        float4 wA = *(const float4*)(ode_b1 + obase);
        float4 wB = *(const float4*)(ode_b1 + obase + 4);
        b1p[0].x = C * wA.x; b1p[0].y = C * wA.y; b1p[1].x = C * wA.z; b1p[1].y = C * wA.w;
        b1p[2].x = C * wB.x; b1p[2].y = C * wB.y; b1p[3].x = C * wB.z; b1p[3].y = C * wB.w;
    }
    // y = 1 - 2*rc where rc = 1/(exp2(a')+1).  pd = sum_j y_j w2_j + b2
    //   = [0.5*b2 + sum_j w2_j] + sum_j rc_j * (-2 w2_j)   (per-lane halves; x2 via dpp sum)
    f2 w2p[8][3];      // -2 * ode_w2 rows
    f2 hb2p[3];        // 0.5*b2 + sum of this lane's raw w2 rows
    #pragma unroll
    for (int s = 0; s < 3; ++s) {
        float2 w = *(const float2*)(ode_b2 + 2 * s);
        hb2p[s].x = 0.5f * w.x; hb2p[s].y = 0.5f * w.y;
    }
    #pragma unroll
    for (int j = 0; j < 8; ++j) {
        const float2* wp = (const float2*)(ode_w2 + (obase + j) * NS);
        #pragma unroll
        for (int s = 0; s < 3; ++s) {
            float2 w = wp[s];
            hb2p[s].x += w.x;          hb2p[s].y += w.y;
            w2p[j][s].x = -2.0f * w.x; w2p[j][s].y = -2.0f * w.y;
        }
    }
    // linear-dynamics constant pairs: d = (v, -om2*x - 2g*v) + pd
    f2 c1p[3], c2p[3];
    float dw[NK];
    #pragma unroll
    for (int k = 0; k < NK; ++k) {
        float w = 6.28318530717958647693f / uni(periods[k]);
        c1p[k].x = 1.0f; c1p[k].y = uni(-(w * w));
        c2p[k].x = 0.0f; c2p[k].y = uni(-2.0f * gammav[k]);
        dw[k]    = uni(dec_w[k]);
    }
    const float addc = uni(dec_b[0] + baseline[0]);

    #pragma unroll
    for (int i = 0; i < NS; ++i)
        #pragma unroll
        for (int p = 0; p < 4; ++p) PIN_V(w1p[i][p]);
    #pragma unroll
    for (int p = 0; p < 4; ++p) PIN_V(b1p[p]);
    #pragma unroll
    for (int j = 0; j < 8; ++j)
        #pragma unroll
        for (int s = 0; s < 3; ++s) PIN_V(w2p[j][s]);
    #pragma unroll
    for (int s = 0; s < 3; ++s) { PIN_V(hb2p[s]); PIN_V(c1p[s]); PIN_V(c2p[s]); }

    // ================= encoder (2-way split: 16 h-units per lane) ============
    float h1r[16];
    #pragma unroll
    for (int q = 0; q < 4; ++q) {
        float4 bv = *(const float4*)(enc_b1 + base16 + 4 * q);
        h1r[4 * q] = bv.x; h1r[4 * q + 1] = bv.y; h1r[4 * q + 2] = bv.z; h1r[4 * q + 3] = bv.w;
    }
    const float4* xp = (const float4*)(expr + (size_t)b * NT);
    #pragma unroll 1
    for (int t4 = 0; t4 < NT / 4; ++t4) {
        float4 xq = xp[t4];
        float xs[4] = {xq.x, xq.y, xq.z, xq.w};
        #pragma unroll
        for (int u4 = 0; u4 < 4; ++u4) {
            const float* wr = enc_w1 + (t4 * 4 + u4) * NH + base16;
            float x = xs[u4];
            #pragma unroll
            for (int q = 0; q < 4; ++q) {
                float4 w = *(const float4*)(wr + 4 * q);
                h1r[4 * q]     = fmaf(x, w.x, h1r[4 * q]);
                h1r[4 * q + 1] = fmaf(x, w.y, h1r[4 * q + 1]);
                h1r[4 * q + 2] = fmaf(x, w.z, h1r[4 * q + 2]);
                h1r[4 * q + 3] = fmaf(x, w.w, h1r[4 * q + 3]);
            }
        }
    }
    // layernorm across all 32 (1-stage cross-lane) + gelu
    {
        float s = 0.f;
        #pragma unroll
        for (int u = 0; u < 16; ++u) s += h1r[u];
        float mu = qsum2(s) * (1.0f / NH);
        float v = 0.f;
        #pragma unroll
        for (int u = 0; u < 16; ++u) { float d = h1r[u] - mu; v = fmaf(d, d, v); }
        float var = qsum2(v) * (1.0f / NH);
        float rstd = rsqrtf(var + 1e-5f);
        #pragma unroll
        for (int q = 0; q < 4; ++q) {
            float4 g = *(const float4*)(ln_g + base16 + 4 * q);
            float4 l = *(const float4*)(ln_b + base16 + 4 * q);
            h1r[4 * q]     = gelu_exact((h1r[4 * q]     - mu) * rstd * g.x + l.x);
            h1r[4 * q + 1] = gelu_exact((h1r[4 * q + 1] - mu) * rstd * g.y + l.y);
            h1r[4 * q + 2] = gelu_exact((h1r[4 * q + 2] - mu) * rstd * g.z + l.z);
            h1r[4 * q + 3] = gelu_exact((h1r[4 * q + 3] - mu) * rstd * g.w + l.w);
        }
    }
    // h2 = gelu(h1 @ w2 + b2): lane owns j2 in [base16, base16+16)
    float acc[16];
    #pragma unroll
    for (int q = 0; q < 4; ++q) {
        float4 bv = *(const float4*)(enc_b2 + base16 + 4 * q);
        acc[4 * q] = bv.x; acc[4 * q + 1] = bv.y; acc[4 * q + 2] = bv.z; acc[4 * q + 3] = bv.w;
    }
    #pragma unroll 1
    for (int u = 0; u < 16; ++u) {
        float mine  = h1r[u];
        float other = dpp_xor1(mine);
        const float* wa = enc_w2 + (base16 + u) * NH + base16;
        const float* wb = enc_w2 + ((16 - base16) + u) * NH + base16;
        #pragma unroll
        for (int q = 0; q < 4; ++q) {
            float4 w1v = *(const float4*)(wa + 4 * q);
            float4 w2v = *(const float4*)(wb + 4 * q);
            acc[4 * q]     = fmaf(mine, w1v.x, fmaf(other, w2v.x, acc[4 * q]));
            acc[4 * q + 1] = fmaf(mine, w1v.y, fmaf(other, w2v.y, acc[4 * q + 1]));
            acc[4 * q + 2] = fmaf(mine, w1v.z, fmaf(other, w2v.z, acc[4 * q + 2]));
            acc[4 * q + 3] = fmaf(mine, w1v.w, fmaf(other, w2v.w, acc[4 * q + 3]));
        }
    }
    // z0 = gelu(acc) @ w3 + b3, 1-stage reduce -> replicated in both lanes
    f2 z[3];
    {
        float zp[NS] = {0.f, 0.f, 0.f, 0.f, 0.f, 0.f};
        #pragma unroll 1
        for (int u = 0; u < 16; ++u) {
            float gm = gelu_exact(acc[u]);
            const float2* wp = (const float2*)(enc_w3 + (base16 + u) * NS);
            float2 w0 = wp[0], w1 = wp[1], w2 = wp[2];
            zp[0] = fmaf(gm, w0.x, zp[0]); zp[1] = fmaf(gm, w0.y, zp[1]);
            zp[2] = fmaf(gm, w1.x, zp[2]); zp[3] = fmaf(gm, w1.y, zp[3]);
            zp[4] = fmaf(gm, w2.x, zp[4]); zp[5] = fmaf(gm, w2.y, zp[5]);
        }
        #pragma unroll
        for (int s = 0; s < 3; ++s) {
            z[s].x = qsum2(zp[2 * s])     + enc_b3[2 * s];
            z[s].y = qsum2(zp[2 * s + 1]) + enc_b3[2 * s + 1];
        }
    }

    auto deriv = [&](const f2 (&zz)[3], f2 (&d)[3]) {
        // a'[p] = C*(b1 + sum_i z_i w1[i][p]) — first fma inits from b1p (no movs)
        f2 a[4];
        #pragma unroll
        for (int p = 0; p < 4; ++p) {
            PK_FMA_LO_I(a[p], zz[0], w1p[0][p], b1p[p]);
            PK_FMA_HI (a[p], zz[0], w1p[1][p]);
        }
        #pragma unroll
        for (int s = 1; s < 3; ++s) {
            #pragma unroll
            for (int p = 0; p < 4; ++p) {
                PK_FMA_LO(a[p], zz[s], w1p[2 * s][p]);
                PK_FMA_HI(a[p], zz[s], w1p[2 * s + 1][p]);
            }
        }
        // rc = 1/(exp2(a')+1)   (y = 1-2rc folded into w2p/hb2p)
        f2 rc[4];
        #pragma unroll
        for (int p = 0; p < 4; ++p) {
            f2 e; e.x = __builtin_amdgcn_exp2f(a[p].x); e.y = __builtin_amdgcn_exp2f(a[p].y);
            f2 r = e + bc2(1.0f);
            rc[p].x = __builtin_amdgcn_rcpf(r.x); rc[p].y = __builtin_amdgcn_rcpf(r.y);
        }
        // pd[s] = hb2p + sum_j rc_j * w2p[j]  — first fma inits from hb2p
        f2 pd[3];
        #pragma unroll
        for (int s = 0; s < 3; ++s) {
            PK_FMA_LO_I(pd[s], rc[0], w2p[0][s], hb2p[s]);
            PK_FMA_HI (pd[s], rc[0], w2p[1][s]);
        }
        #pragma unroll
        for (int p = 1; p < 4; ++p) {
            #pragma unroll
            for (int s = 0; s < 3; ++s) {
                PK_FMA_LO(pd[s], rc[p], w2p[2 * p][s]);
                PK_FMA_HI(pd[s], rc[p], w2p[2 * p + 1][s]);
            }
        }
        // cross-lane reduce + packed linear assembly:
        //   t = (zz.y*1 + pd.x, zz.x*(-om2) + pd.y); d = (t.x, zz.y*(-2g)+t.y)
        #pragma unroll
        for (int s = 0; s < 3; ++s) {
            f2 o; o.x = dpp_xor1(pd[s].x); o.y = dpp_xor1(pd[s].y);
            pd[s] += o;
            f2 t;
            PK_FMA_SWAP_I(t, zz[s], c1p[s], pd[s]);
            d[s] = fma2(zz[s], c2p[s], t);
        }
    };

    // ================= t = 0 outputs =================
    float amp[NK];
    {
        float eh = addc;
        #pragma unroll
        for (int k = 0; k < NK; ++k) {
            float xx = z[k].x;
            amp[k] = xx * xx;
            eh = fmaf(xx, dw[k], eh);
        }
        float* tp = out_tr + (size_t)b * NS;
        if (sub == 0) {
            out_eh[(size_t)b * NT] = eh;
            float2 s0 = {z[0].x, z[0].y}, s1 = {z[1].x, z[1].y};
            *(float2*)tp = s0; *(float2*)(tp + 2) = s1;
        } else {
            float2 s2 = {z[2].x, z[2].y};
            *(float2*)(tp + 4) = s2;
        }
    }

    // ================= integrate =================
    float te_prev = t_eval[0];
    #pragma unroll 1
    for (int t = 1; t < NT; ++t) {
        const float te  = t_eval[t];
        const float dt  = te - te_prev;
        te_prev = te;
        const float hh  = dt * (1.0f / NSUB);
        const float hh2 = 0.5f * hh;
        const float hh6 = hh * (1.0f / 6.0f);
        f2 hh2p = bc2(hh2), hhp = bc2(hh), hh6p = bc2(hh6);
        #pragma unroll 1
        for (int ss = 0; ss < NSUB; ++ss) {
            f2 d[3], zt[3], zs[3];
            deriv(z, d);                                        // k1
            #pragma unroll
            for (int s = 0; s < 3; ++s) { zs[s] = d[s]; zt[s] = fma2(hh2p, d[s], z[s]); }
            deriv(zt, d);                                       // k2
            #pragma unroll
            for (int s = 0; s < 3; ++s) { zs[s] = fma2(bc2(2.f), d[s], zs[s]); zt[s] = fma2(hh2p, d[s], z[s]); }
            deriv(zt, d);                                       // k3
            #pragma unroll
            for (int s = 0; s < 3; ++s) { zs[s] = fma2(bc2(2.f), d[s], zs[s]); zt[s] = fma2(hhp, d[s], z[s]); }
            deriv(zt, d);                                       // k4
            #pragma unroll
            for (int s = 0; s < 3; ++s) z[s] = fma2(hh6p, zs[s] + d[s], z[s]);
        }
        float eh = addc;
        #pragma unroll
        for (int k = 0; k < NK; ++k) {
            float xx = z[k].x;
            amp[k] = fmaf(xx, xx, amp[k]);
            eh = fmaf(xx, dw[k], eh);
        }
        float* tp = out_tr + ((size_t)t * NB + b) * NS;
        if (sub == 0) {
            out_eh[(size_t)b * NT + t] = eh;
            float2 s0 = {z[0].x, z[0].y}, s1 = {z[1].x, z[1].y};
            *(float2*)tp = s0; *(float2*)(tp + 2) = s1;
        } else {
            float2 s2 = {z[2].x, z[2].y};
            *(float2*)(tp + 4) = s2;
        }
    }

    if (sub == 0) {
        out_amp[(size_t)b * NK]     = sqrtf(amp[0] * (1.0f / NT));
        out_amp[(size_t)b * NK + 1] = sqrtf(amp[1] * (1.0f / NT));
    } else {
        out_amp[(size_t)b * NK + 2] = sqrtf(amp[2] * (1.0f / NT));
    }
}

extern "C" void kernel_launch(void* const* d_in, const int* in_sizes, int n_in,
                              void* d_out, int out_size, void* d_ws, size_t ws_size,
                              hipStream_t stream) {
    pinod_kernel<<<(NB * 2) / 256, 256, 0, stream>>>(
        (const float*)d_in[0],  (const float*)d_in[1],  (const float*)d_in[2],
        (const float*)d_in[3],  (const float*)d_in[4],  (const float*)d_in[5],
        (const float*)d_in[6],  (const float*)d_in[7],  (const float*)d_in[8],
        (const float*)d_in[9],  (const float*)d_in[10], (const float*)d_in[11],
        (const float*)d_in[12], (const float*)d_in[13], (const float*)d_in[14],
        (const float*)d_in[15], (const float*)d_in[16], (const float*)d_in[17],
        (const float*)d_in[18], (float*)d_out);
}